// Round 1
// baseline (2306.244 us; speedup 1.0000x reference)
//
#include <hip/hip_runtime.h>
#include <stdint.h>

#define NN 20000
#define NE 80000
#define DD 1024

typedef __bf16 bf16x8 __attribute__((ext_vector_type(8)));
typedef float f32x4 __attribute__((ext_vector_type(4)));
typedef unsigned short u16;
typedef unsigned int u32;

// round-half-up f32->bf16, packed pair in one u32 (low = f0, high = f1)
__device__ __forceinline__ u32 pack2bf(float f0, float f1) {
  u32 u0 = __float_as_uint(f0) + 0x8000u;
  u32 u1 = __float_as_uint(f1) + 0x8000u;
  return __builtin_amdgcn_perm(u1, u0, 0x07060302u);
}

// edge_index may be int64 (stride 2 in int32 words) or int32 (stride 1).
// For int64 little-endian non-negative values, every odd int32 word is 0.
__global__ void detect_stride_k(const int* __restrict__ ei, int* flag) {
  if (threadIdx.x == 0) {
    int nz = 0;
    for (int i = 1; i < 128; i += 2) nz |= ei[i];
    *flag = (nz == 0) ? 2 : 1;
  }
}

// in: fp32 [1024,1024] row-major -> out: bf16 [1024,1024] transposed
__global__ void transpose_cvt_k(const float* __restrict__ in, u16* __restrict__ out) {
  __shared__ float tile[32][33];
  int bx = blockIdx.x * 32;
  int by = blockIdx.y * 32;
  int tx = threadIdx.x & 31, ty = threadIdx.x >> 5;
#pragma unroll
  for (int s = 0; s < 4; s++)
    tile[ty + s * 8][tx] = in[(size_t)(by + ty + s * 8) * DD + bx + tx];
  __syncthreads();
#pragma unroll
  for (int s = 0; s < 4; s++) {
    float f = tile[tx][ty + s * 8];
    out[(size_t)(bx + ty + s * 8) * DD + by + tx] =
        (u16)((__float_as_uint(f) + 0x8000u) >> 16);
  }
}

__global__ void count_edges_k(const int* __restrict__ ei, const int* __restrict__ sflag,
                              int* __restrict__ cnt) {
  int e = blockIdx.x * 256 + threadIdx.x;
  if (e < NE) {
    int s = *sflag;
    int c = ei[(size_t)s * (NE + e)];
    atomicAdd(&cnt[c], 1);
  }
}

__global__ void divide_mean_k(float4* __restrict__ S1, const int* __restrict__ cnt) {
  int i = blockIdx.x * 256 + threadIdx.x;  // over N*D/4
  if (i < NN * DD / 4) {
    int n = i >> 8;  // 256 float4 per row
    float inv = 1.0f / (float)max(cnt[n], 1);
    float4 v = S1[i];
    v.x *= inv; v.y *= inv; v.z *= inv; v.w *= inv;
    S1[i] = v;
  }
}

// C[M,1024] = A(f32,[M,1024]) @ B^T(bf16,[1024 n][1024 k])   (+ optional 2nd source)
// EPI 0: C = acc + bias            -> Cout
// EPI 1: z = relu(acc + P[row[e]]); atomicAdd(S1[col[e]], z)   (no Cout)
// EPI 2: C = acc + (cnt>0 ? bias : 0) -> Cout
// EPI 3: C = relu(acc + bias)      -> Cout
template <int EPI, int NSRC>
__global__ __launch_bounds__(256) void gemm_k(
    const float* __restrict__ A0, const float* __restrict__ A1,
    const u16* __restrict__ B0, const u16* __restrict__ B1,
    int M,
    const float* __restrict__ bias, float* __restrict__ Cout,
    const float* __restrict__ P, float* __restrict__ S1,
    const int* __restrict__ eidx, const int* __restrict__ sflag,
    const int* __restrict__ cnt) {
  // LDS tiles: 128 rows x 32 k of bf16, XOR-swizzled 16B chunks:
  // chunk(row, kc) at row*32 + (kc ^ (row&3) ^ ((row>>2)&3))*8  (ushort units)
  __shared__ __align__(16) u16 As[128 * 32];
  __shared__ __align__(16) u16 Bs[128 * 32];

  const int tid = threadIdx.x;
  const int lane = tid & 63;
  const int wv = tid >> 6;
  const int wm = wv >> 1, wn = wv & 1;  // 2x2 waves, 64x64 each
  const int mblk = blockIdx.y, nblk = blockIdx.x;
  const int lrow = lane & 15, kq = lane >> 4;

  int ss = 1;
  if constexpr (EPI == 1) ss = *sflag;

  f32x4 acc[4][4] = {};

  for (int s = 0; s < NSRC; s++) {
    const float* Ag = (s == 0) ? A0 : A1;
    const u16* Bg = (s == 0) ? B0 : B1;
    for (int kt = 0; kt < DD / 32; kt++) {
      // stage A: 128x32 fp32 -> bf16, 4 float4/thread, coalesced
#pragma unroll
      for (int it = 0; it < 4; it++) {
        int idx = tid + it * 256;
        int ar = idx >> 3, j = idx & 7;  // j = float4 slot in row (k = 4j..4j+3)
        int grow = mblk * 128 + ar;
        float4 f = {0.f, 0.f, 0.f, 0.f};
        if (grow < M)
          f = *(const float4*)(Ag + (size_t)grow * DD + kt * 32 + j * 4);
        u32 p0 = pack2bf(f.x, f.y);
        u32 p1 = pack2bf(f.z, f.w);
        int sw = (j >> 1) ^ (ar & 3) ^ ((ar >> 2) & 3);
        *(uint2*)&As[ar * 32 + sw * 8 + (j & 1) * 4] = make_uint2(p0, p1);
      }
      // stage B: already bf16 B^T, pure 16B copies, 2/thread
#pragma unroll
      for (int it = 0; it < 2; it++) {
        int idx = tid + it * 256;
        int br = idx >> 2, j = idx & 3;  // j = 16B chunk (k = 8j..8j+7)
        uint4 v = *(const uint4*)(Bg + (size_t)(nblk * 128 + br) * DD + kt * 32 + j * 8);
        int sw = j ^ (br & 3) ^ ((br >> 2) & 3);
        *(uint4*)&Bs[br * 32 + sw * 8] = v;
      }
      __syncthreads();
      bf16x8 af[4], bfr[4];
#pragma unroll
      for (int i = 0; i < 4; i++) {
        int m = wm * 64 + i * 16 + lrow;
        af[i] = *(const bf16x8*)&As[m * 32 + ((kq ^ (m & 3) ^ ((m >> 2) & 3)) * 8)];
        int n = wn * 64 + i * 16 + lrow;
        bfr[i] = *(const bf16x8*)&Bs[n * 32 + ((kq ^ (n & 3) ^ ((n >> 2) & 3)) * 8)];
      }
#pragma unroll
      for (int i = 0; i < 4; i++)
#pragma unroll
        for (int j = 0; j < 4; j++)
          acc[i][j] = __builtin_amdgcn_mfma_f32_16x16x32_bf16(af[i], bfr[j], acc[i][j], 0, 0, 0);
      __syncthreads();
    }
  }

  // epilogue: C/D layout col=lane&15, row=(lane>>4)*4+reg
#pragma unroll
  for (int i = 0; i < 4; i++) {
#pragma unroll
    for (int r = 0; r < 4; r++) {
      int grow = mblk * 128 + wm * 64 + i * 16 + kq * 4 + r;
      if (grow >= M) continue;
      int erow = 0, ecol = 0;
      if constexpr (EPI == 1) {
        erow = eidx[(size_t)ss * grow];
        ecol = eidx[(size_t)ss * (NE + grow)];
      }
#pragma unroll
      for (int j = 0; j < 4; j++) {
        int gcol = nblk * 128 + wn * 64 + j * 16 + lrow;
        float v = acc[i][j][r];
        if constexpr (EPI == 0) {
          Cout[(size_t)grow * DD + gcol] = v + bias[gcol];
        } else if constexpr (EPI == 1) {
          float z = fmaxf(v + P[(size_t)erow * DD + gcol], 0.f);
          atomicAdd(&S1[(size_t)ecol * DD + gcol], z);
        } else if constexpr (EPI == 2) {
          float b = (cnt[grow] > 0) ? bias[gcol] : 0.f;
          Cout[(size_t)grow * DD + gcol] = v + b;
        } else {
          Cout[(size_t)grow * DD + gcol] = fmaxf(v + bias[gcol], 0.f);
        }
      }
    }
  }
}

extern "C" void kernel_launch(void* const* d_in, const int* in_sizes, int n_in,
                              void* d_out, int out_size, void* d_ws, size_t ws_size,
                              hipStream_t stream) {
  const float* x   = (const float*)d_in[0];
  const int*   ei  = (const int*)d_in[1];
  const float* ea  = (const float*)d_in[2];
  const float* W1a = (const float*)d_in[3];
  const float* b1a = (const float*)d_in[4];
  const float* W1b = (const float*)d_in[5];
  const float* b1b = (const float*)d_in[6];
  const float* W2a = (const float*)d_in[7];
  const float* b2a = (const float*)d_in[8];
  const float* W2b = (const float*)d_in[9];
  const float* b2b = (const float*)d_in[10];
  float* out = (float*)d_out;

  char* ws = (char*)d_ws;
  size_t off = 0;
  const size_t WSZ = (size_t)DD * DD;  // one 1024x1024 piece
  u16* W1aT_t = (u16*)(ws + off); off += WSZ * 2;
  u16* W1aT_b = (u16*)(ws + off); off += WSZ * 2;
  u16* W1bT   = (u16*)(ws + off); off += WSZ * 2;
  u16* W2aT_t = (u16*)(ws + off); off += WSZ * 2;
  u16* W2aT_b = (u16*)(ws + off); off += WSZ * 2;
  u16* W2bT   = (u16*)(ws + off); off += WSZ * 2;
  float* bufA = (float*)(ws + off); off += (size_t)NN * DD * 4;  // P, then M
  float* bufB = (float*)(ws + off); off += (size_t)NN * DD * 4;  // S1, then out2
  int* cnt    = (int*)(ws + off);  off += (size_t)NN * 4;
  int* sflag  = (int*)(ws + off);  off += 256;
  if (ws_size < off) return;  // ws too small: leave output poisoned as a signal

  dim3 tb(256);
  dim3 tg(32, 32);
  transpose_cvt_k<<<tg, tb, 0, stream>>>(W1a, W1aT_t);
  transpose_cvt_k<<<tg, tb, 0, stream>>>(W1a + WSZ, W1aT_b);
  transpose_cvt_k<<<tg, tb, 0, stream>>>(W1b, W1bT);
  transpose_cvt_k<<<tg, tb, 0, stream>>>(W2a, W2aT_t);
  transpose_cvt_k<<<tg, tb, 0, stream>>>(W2a + WSZ, W2aT_b);
  transpose_cvt_k<<<tg, tb, 0, stream>>>(W2b, W2bT);

  detect_stride_k<<<1, 64, 0, stream>>>(ei, sflag);
  hipMemsetAsync(bufB, 0, (size_t)NN * DD * 4, stream);
  hipMemsetAsync(cnt, 0, (size_t)NN * 4, stream);
  count_edges_k<<<(NE + 255) / 256, tb, 0, stream>>>(ei, sflag, cnt);

  dim3 gN(8, (NN + 127) / 128);  // 8 x 157
  dim3 gE(8, NE / 128);          // 8 x 625

  // GEMM1: P = x @ W1a_top + b1a        -> bufA
  gemm_k<0, 1><<<gN, tb, 0, stream>>>(x, nullptr, W1aT_t, nullptr, NN,
                                      b1a, bufA, nullptr, nullptr, nullptr, nullptr, nullptr);
  // GEMM2: relu(ea@W1a_bot + P[row]) scatter-add -> S1 (bufB)
  gemm_k<1, 1><<<gE, tb, 0, stream>>>(ea, nullptr, W1aT_b, nullptr, NE,
                                      nullptr, nullptr, bufA, bufB, ei, sflag, nullptr);
  // S1 /= max(cnt,1)
  divide_mean_k<<<(NN * DD / 4 + 255) / 256, tb, 0, stream>>>((float4*)bufB, cnt);
  // GEMM3: M = S1bar @ W1b + mask*b1b   -> bufA (P dead)
  gemm_k<2, 1><<<gN, tb, 0, stream>>>(bufB, nullptr, W1bT, nullptr, NN,
                                      b1b, bufA, nullptr, nullptr, nullptr, nullptr, cnt);
  // GEMM4: out2 = relu(x@W2a_top + M@W2a_bot + b2a) -> bufB (S1 dead)
  gemm_k<3, 2><<<gN, tb, 0, stream>>>(x, bufA, W2aT_t, W2aT_b, NN,
                                      b2a, bufB, nullptr, nullptr, nullptr, nullptr, nullptr);
  // GEMM5: out = out2 @ W2b + b2b       -> d_out
  gemm_k<0, 1><<<gN, tb, 0, stream>>>(bufB, nullptr, W2bT, nullptr, NN,
                                      b2b, out, nullptr, nullptr, nullptr, nullptr, nullptr);
}

// Round 2
// 1349.551 us; speedup vs baseline: 1.7089x; 1.7089x over previous
//
#include <hip/hip_runtime.h>
#include <stdint.h>

#define NN 20000
#define NE 80000
#define DD 1024

typedef __bf16 bf16x8 __attribute__((ext_vector_type(8)));
typedef float f32x4 __attribute__((ext_vector_type(4)));
typedef unsigned short u16;
typedef unsigned int u32;

__device__ __forceinline__ float bf2f(u16 v) { return __uint_as_float(((u32)v) << 16); }
__device__ __forceinline__ u16 f2bf(float f) { return (u16)((__float_as_uint(f) + 0x8000u) >> 16); }
__device__ __forceinline__ u32 pack2bf(float f0, float f1) {
  u32 u0 = __float_as_uint(f0) + 0x8000u;
  u32 u1 = __float_as_uint(f1) + 0x8000u;
  return __builtin_amdgcn_perm(u1, u0, 0x07060302u);
}

// async 16B global->LDS DMA; LDS dest = wave-uniform base + lane*16
__device__ __forceinline__ void lds_dma16(const u16* g, u16* l) {
  __builtin_amdgcn_global_load_lds((const __attribute__((address_space(1))) u32*)g,
                                   (__attribute__((address_space(3))) u32*)l, 16, 0, 0);
}

// edge_index may be int64 (stride 2 in int32 words) or int32 (stride 1)
__global__ void detect_stride_k(const int* __restrict__ ei, int* flag) {
  if (threadIdx.x == 0) {
    int nz = 0;
    for (int i = 1; i < 128; i += 2) nz |= ei[i];
    *flag = (nz == 0) ? 2 : 1;
  }
}

// fp32 [1024,1024] row-major -> bf16 transposed [n][k]
__global__ void transpose_cvt_k(const float* __restrict__ in, u16* __restrict__ out) {
  __shared__ float tile[32][33];
  int bx = blockIdx.x * 32, by = blockIdx.y * 32;
  int tx = threadIdx.x & 31, ty = threadIdx.x >> 5;
#pragma unroll
  for (int s = 0; s < 4; s++)
    tile[ty + s * 8][tx] = in[(size_t)(by + ty + s * 8) * DD + bx + tx];
  __syncthreads();
#pragma unroll
  for (int s = 0; s < 4; s++)
    out[(size_t)(bx + ty + s * 8) * DD + by + tx] = f2bf(tile[tx][ty + s * 8]);
}

__global__ void cvt_bf16_k(const float4* __restrict__ in, ushort4* __restrict__ out, int n4) {
  int i = blockIdx.x * 256 + threadIdx.x;
  if (i < n4) {
    float4 f = in[i];
    ushort4 o;
    o.x = f2bf(f.x); o.y = f2bf(f.y); o.z = f2bf(f.z); o.w = f2bf(f.w);
    out[i] = o;
  }
}

__global__ void count_edges_k(const int* __restrict__ ei, const int* __restrict__ sflag,
                              int* __restrict__ cnt) {
  int e = blockIdx.x * 256 + threadIdx.x;
  if (e < NE) {
    int s = *sflag;
    atomicAdd(&cnt[ei[(size_t)s * (NE + e)]], 1);
  }
}

// single block, 1024 threads: exclusive prefix sum of cnt -> rowptr, ofs
__global__ __launch_bounds__(1024) void scan_k(const int* __restrict__ cnt,
                                               int* __restrict__ rowptr, int* __restrict__ ofs) {
  __shared__ int part[1024];
  int t = threadIdx.x;
  int base = t * 20;
  int loc[20];
  int s = 0;
#pragma unroll
  for (int i = 0; i < 20; i++) {
    int v = (base + i < NN) ? cnt[base + i] : 0;
    loc[i] = s; s += v;
  }
  part[t] = s;
  __syncthreads();
  for (int d = 1; d < 1024; d <<= 1) {
    int v = (t >= d) ? part[t - d] : 0;
    __syncthreads();
    part[t] += v;
    __syncthreads();
  }
  int excl = (t > 0) ? part[t - 1] : 0;
#pragma unroll
  for (int i = 0; i < 20; i++)
    if (base + i < NN) { rowptr[base + i] = excl + loc[i]; ofs[base + i] = excl + loc[i]; }
  if (t == 1023) rowptr[NN] = part[1023];
}

__global__ void scatter_k(const int* __restrict__ ei, const int* __restrict__ sflag,
                          int* __restrict__ ofs, int* __restrict__ perm) {
  int e = blockIdx.x * 256 + threadIdx.x;
  if (e < NE) {
    int s = *sflag;
    int c = ei[(size_t)s * (NE + e)];
    perm[atomicAdd(&ofs[c], 1)] = e;
  }
}

// mean over each node's edges of h (bf16 [E,1024]) -> sbar (bf16 [N,1024])
__global__ void seg_mean_k(const u16* __restrict__ h, const int* __restrict__ rowptr,
                           const int* __restrict__ perm, u16* __restrict__ sbar) {
  int n = blockIdx.x, t = threadIdx.x;
  int beg = rowptr[n], end = rowptr[n + 1];
  float a0 = 0, a1 = 0, a2 = 0, a3 = 0;
  for (int i = beg; i < end; i++) {
    int e = perm[i];
    ushort4 v = *(const ushort4*)(h + (size_t)e * DD + t * 4);
    a0 += bf2f(v.x); a1 += bf2f(v.y); a2 += bf2f(v.z); a3 += bf2f(v.w);
  }
  float inv = (end > beg) ? 1.0f / (float)(end - beg) : 0.0f;
  ushort4 o;
  o.x = f2bf(a0 * inv); o.y = f2bf(a1 * inv); o.z = f2bf(a2 * inv); o.w = f2bf(a3 * inv);
  *(ushort4*)(sbar + (size_t)n * DD + t * 4) = o;
}

// C[M,1024] = A @ B^T(bf16 [n][k]).  A bf16 (DMA-staged) or fp32 (VALU-staged).
// LDS layout: 16B chunk (row,kc) at chunk index row*4 + (kc ^ ((row>>1)&3)).
// EPI 0: Cout(f32) = acc + bias
// EPI 1: Hout(bf16)[e] = relu(acc + P[row[e]])   (edge GEMM)
// EPI 2: Cbf = acc + (cnt>0 ? bias : 0)
// EPI 3: Cbf = relu(acc + bias)
// EPI 4: Cbf = acc + bias
template <int EPI, int NSRC, bool AF32>
__global__ __launch_bounds__(256) void gemm_k(
    const void* __restrict__ A0, const void* __restrict__ A1,
    const u16* __restrict__ B0, const u16* __restrict__ B1, int M,
    const float* __restrict__ bias, float* __restrict__ Cout, u16* __restrict__ Cbf,
    const u16* __restrict__ Pg, u16* __restrict__ Hout,
    const int* __restrict__ eidx, const int* __restrict__ sflag,
    const int* __restrict__ cnt) {
  __shared__ __align__(16) u16 As[128 * 32];
  __shared__ __align__(16) u16 Bs[128 * 32];

  const int tid = threadIdx.x;
  const int lane = tid & 63;
  const int wv = tid >> 6;
  const int wm = wv >> 1, wn = wv & 1;  // 2x2 waves, 64x64 each
  const int mblk = blockIdx.y, nblk = blockIdx.x;
  const int lrow = lane & 15, kq = lane >> 4;

  int ss = 1;
  if constexpr (EPI == 1) ss = *sflag;

  // DMA staging precompute: segment s = wv*2+r covers chunks s*64..s*64+63
  size_t a_goff[2], b_goff[2];
  u16 *a_lb[2], *b_lb[2];
  // VALU staging precompute (AF32): 4 float4 per thread
  int va_row[4], va_dst[4];
#pragma unroll
  for (int r = 0; r < 2; r++) {
    int p = (wv * 2 + r) * 64 + lane;
    int row = p >> 2, c = p & 3;
    int kc = c ^ ((row >> 1) & 3);
    a_goff[r] = (size_t)min(mblk * 128 + row, M - 1) * DD + kc * 8;
    b_goff[r] = (size_t)(nblk * 128 + row) * DD + kc * 8;
    a_lb[r] = &As[(wv * 2 + r) * 512];
    b_lb[r] = &Bs[(wv * 2 + r) * 512];
  }
  if constexpr (AF32) {
#pragma unroll
    for (int it = 0; it < 4; it++) {
      int idx = tid + it * 256;
      int ar = idx >> 3, j = idx & 7;  // row, float4 slot (k=4j..4j+3)
      va_row[it] = min(mblk * 128 + ar, M - 1);
      int chunk = ar * 4 + ((j >> 1) ^ ((ar >> 1) & 3));
      va_dst[it] = chunk * 8 + (j & 1) * 4;
    }
  }

  // fragment LDS offsets (u16 units)
  int a_fo[4], b_fo[4];
#pragma unroll
  for (int i = 0; i < 4; i++) {
    int m = wm * 64 + i * 16 + lrow;
    a_fo[i] = (m * 4 + (kq ^ ((m >> 1) & 3))) * 8;
    int n = wn * 64 + i * 16 + lrow;
    b_fo[i] = (n * 4 + (kq ^ ((n >> 1) & 3))) * 8;
  }

  f32x4 acc[4][4] = {};

  for (int src = 0; src < NSRC; src++) {
    const void* Ag = src ? A1 : A0;
    const u16* Bg = src ? B1 : B0;
    for (int kt = 0; kt < DD / 32; kt++) {
      if constexpr (AF32) {
        const float* Af = (const float*)Ag;
#pragma unroll
        for (int it = 0; it < 4; it++) {
          int idx = tid + it * 256;
          int j = idx & 7;
          float4 f = *(const float4*)(Af + (size_t)va_row[it] * DD + kt * 32 + j * 4);
          *(uint2*)&As[va_dst[it]] = make_uint2(pack2bf(f.x, f.y), pack2bf(f.z, f.w));
        }
      } else {
        const u16* Ab = (const u16*)Ag;
#pragma unroll
        for (int r = 0; r < 2; r++)
          lds_dma16(Ab + a_goff[r] + (size_t)kt * 32, a_lb[r]);
      }
#pragma unroll
      for (int r = 0; r < 2; r++)
        lds_dma16(Bg + b_goff[r] + (size_t)kt * 32, b_lb[r]);
      __syncthreads();
      bf16x8 af[4], bf[4];
#pragma unroll
      for (int i = 0; i < 4; i++) {
        af[i] = *(const bf16x8*)&As[a_fo[i]];
        bf[i] = *(const bf16x8*)&Bs[b_fo[i]];
      }
#pragma unroll
      for (int i = 0; i < 4; i++)
#pragma unroll
        for (int j = 0; j < 4; j++)
          acc[i][j] = __builtin_amdgcn_mfma_f32_16x16x32_bf16(af[i], bf[j], acc[i][j], 0, 0, 0);
      __syncthreads();
    }
  }

  // epilogue: C/D layout col=lane&15, row=(lane>>4)*4+reg
#pragma unroll
  for (int i = 0; i < 4; i++) {
#pragma unroll
    for (int r = 0; r < 4; r++) {
      int grow = mblk * 128 + wm * 64 + i * 16 + kq * 4 + r;
      if (grow >= M) continue;
      int erow = 0;
      if constexpr (EPI == 1) erow = eidx[(size_t)ss * grow];
#pragma unroll
      for (int j = 0; j < 4; j++) {
        int gcol = nblk * 128 + wn * 64 + j * 16 + lrow;
        float v = acc[i][j][r];
        if constexpr (EPI == 0) {
          Cout[(size_t)grow * DD + gcol] = v + bias[gcol];
        } else if constexpr (EPI == 1) {
          float z = fmaxf(v + bf2f(Pg[(size_t)erow * DD + gcol]), 0.0f);
          Hout[(size_t)grow * DD + gcol] = f2bf(z);
        } else if constexpr (EPI == 2) {
          float b = (cnt[grow] > 0) ? bias[gcol] : 0.0f;
          Cbf[(size_t)grow * DD + gcol] = f2bf(v + b);
        } else if constexpr (EPI == 3) {
          Cbf[(size_t)grow * DD + gcol] = f2bf(fmaxf(v + bias[gcol], 0.0f));
        } else {
          Cbf[(size_t)grow * DD + gcol] = f2bf(v + bias[gcol]);
        }
      }
    }
  }
}

extern "C" void kernel_launch(void* const* d_in, const int* in_sizes, int n_in,
                              void* d_out, int out_size, void* d_ws, size_t ws_size,
                              hipStream_t stream) {
  const float* x   = (const float*)d_in[0];
  const int*   ei  = (const int*)d_in[1];
  const float* ea  = (const float*)d_in[2];
  const float* W1a = (const float*)d_in[3];
  const float* b1a = (const float*)d_in[4];
  const float* W1b = (const float*)d_in[5];
  const float* b1b = (const float*)d_in[6];
  const float* W2a = (const float*)d_in[7];
  const float* b2a = (const float*)d_in[8];
  const float* W2b = (const float*)d_in[9];
  const float* b2b = (const float*)d_in[10];
  float* out = (float*)d_out;

  char* ws = (char*)d_ws;
  size_t off = 0;
  const size_t WSZ = (size_t)DD * DD;
  u16* W1aT_t = (u16*)(ws + off); off += WSZ * 2;
  u16* W1aT_b = (u16*)(ws + off); off += WSZ * 2;
  u16* W1bT   = (u16*)(ws + off); off += WSZ * 2;
  u16* W2aT_t = (u16*)(ws + off); off += WSZ * 2;
  u16* W2aT_b = (u16*)(ws + off); off += WSZ * 2;
  u16* W2bT   = (u16*)(ws + off); off += WSZ * 2;
  u16* xb   = (u16*)(ws + off); off += (size_t)NN * DD * 2;
  u16* bufP = (u16*)(ws + off); off += (size_t)NN * DD * 2;  // P -> Sbar -> out2
  u16* bufM = (u16*)(ws + off); off += (size_t)NN * DD * 2;  // M
  u16* h    = (u16*)(ws + off); off += (size_t)NE * DD * 2;
  int* cnt    = (int*)(ws + off); off += (size_t)NN * 4;
  int* rowptr = (int*)(ws + off); off += (size_t)(NN + 1) * 4;
  int* ofs    = (int*)(ws + off); off += (size_t)NN * 4;
  int* perm   = (int*)(ws + off); off += (size_t)NE * 4;
  int* sflag  = (int*)(ws + off); off += 256;
  if (ws_size < off) return;

  dim3 tb(256);
  dim3 tg(32, 32);
  transpose_cvt_k<<<tg, tb, 0, stream>>>(W1a, W1aT_t);
  transpose_cvt_k<<<tg, tb, 0, stream>>>(W1a + WSZ, W1aT_b);
  transpose_cvt_k<<<tg, tb, 0, stream>>>(W1b, W1bT);
  transpose_cvt_k<<<tg, tb, 0, stream>>>(W2a, W2aT_t);
  transpose_cvt_k<<<tg, tb, 0, stream>>>(W2a + WSZ, W2aT_b);
  transpose_cvt_k<<<tg, tb, 0, stream>>>(W2b, W2bT);

  cvt_bf16_k<<<NN * DD / 4 / 256, tb, 0, stream>>>((const float4*)x, (ushort4*)xb, NN * DD / 4);

  detect_stride_k<<<1, 64, 0, stream>>>(ei, sflag);
  hipMemsetAsync(cnt, 0, (size_t)NN * 4, stream);
  count_edges_k<<<(NE + 255) / 256, tb, 0, stream>>>(ei, sflag, cnt);
  scan_k<<<1, 1024, 0, stream>>>(cnt, rowptr, ofs);
  scatter_k<<<(NE + 255) / 256, tb, 0, stream>>>(ei, sflag, ofs, perm);

  dim3 gN(8, (NN + 127) / 128);
  dim3 gE(8, NE / 128);

  // G1: P = xb @ W1a_top + b1a -> bufP (bf16)
  gemm_k<4, 1, false><<<gN, tb, 0, stream>>>(xb, nullptr, W1aT_t, nullptr, NN,
                                             b1a, nullptr, bufP, nullptr, nullptr,
                                             nullptr, nullptr, nullptr);
  // G2: h = relu(ea @ W1a_bot + P[row]) -> h (bf16), fp32 A staging
  gemm_k<1, 1, true><<<gE, tb, 0, stream>>>(ea, nullptr, W1aT_b, nullptr, NE,
                                            nullptr, nullptr, nullptr, bufP, h,
                                            ei, sflag, nullptr);
  // Sbar = segment-mean of h -> bufP (P dead)
  seg_mean_k<<<NN, tb, 0, stream>>>(h, rowptr, perm, bufP);
  // G3: M = Sbar @ W1b + mask*b1b -> bufM (bf16)
  gemm_k<2, 1, false><<<gN, tb, 0, stream>>>(bufP, nullptr, W1bT, nullptr, NN,
                                             b1b, nullptr, bufM, nullptr, nullptr,
                                             nullptr, nullptr, cnt);
  // G4: out2 = relu(xb@W2a_top + M@W2a_bot + b2a) -> bufP (Sbar dead)
  gemm_k<3, 2, false><<<gN, tb, 0, stream>>>(xb, bufM, W2aT_t, W2aT_b, NN,
                                             b2a, nullptr, bufP, nullptr, nullptr,
                                             nullptr, nullptr, nullptr);
  // G5: out = out2 @ W2b + b2b -> d_out (fp32)
  gemm_k<0, 1, false><<<gN, tb, 0, stream>>>(bufP, nullptr, W2bT, nullptr, NN,
                                             b2b, out, nullptr, nullptr, nullptr,
                                             nullptr, nullptr, nullptr);
}

// Round 3
// 1324.825 us; speedup vs baseline: 1.7408x; 1.0187x over previous
//
#include <hip/hip_runtime.h>
#include <stdint.h>

#define NN 20000
#define NE 80000
#define DD 1024

typedef __bf16 bf16x8 __attribute__((ext_vector_type(8)));
typedef float f32x4 __attribute__((ext_vector_type(4)));
typedef unsigned short u16;
typedef unsigned int u32;

__device__ __forceinline__ float bf2f(u16 v) { return __uint_as_float(((u32)v) << 16); }
__device__ __forceinline__ u16 f2bf(float f) { return (u16)((__float_as_uint(f) + 0x8000u) >> 16); }

// async 16B global->LDS DMA; LDS dest = wave-uniform base + lane*16
__device__ __forceinline__ void lds_dma16(const u16* g, u16* l) {
  __builtin_amdgcn_global_load_lds((const __attribute__((address_space(1))) u32*)g,
                                   (__attribute__((address_space(3))) u32*)l, 16, 0, 0);
}

// edge_index may be int64 (stride 2 in int32 words) or int32 (stride 1)
__global__ void detect_stride_k(const int* __restrict__ ei, int* flag) {
  if (threadIdx.x == 0) {
    int nz = 0;
    for (int i = 1; i < 128; i += 2) nz |= ei[i];
    *flag = (nz == 0) ? 2 : 1;
  }
}

// fp32 [1024,1024] row-major -> bf16 transposed [n][k]
__global__ void transpose_cvt_k(const float* __restrict__ in, u16* __restrict__ out) {
  __shared__ float tile[32][33];
  int bx = blockIdx.x * 32, by = blockIdx.y * 32;
  int tx = threadIdx.x & 31, ty = threadIdx.x >> 5;
#pragma unroll
  for (int s = 0; s < 4; s++)
    tile[ty + s * 8][tx] = in[(size_t)(by + ty + s * 8) * DD + bx + tx];
  __syncthreads();
#pragma unroll
  for (int s = 0; s < 4; s++)
    out[(size_t)(bx + ty + s * 8) * DD + by + tx] = f2bf(tile[tx][ty + s * 8]);
}

__global__ void cvt_bf16_k(const float4* __restrict__ in, ushort4* __restrict__ out, int n4) {
  int i = blockIdx.x * 256 + threadIdx.x;
  if (i < n4) {
    float4 f = in[i];
    ushort4 o;
    o.x = f2bf(f.x); o.y = f2bf(f.y); o.z = f2bf(f.z); o.w = f2bf(f.w);
    out[i] = o;
  }
}

__global__ void count_edges_k(const int* __restrict__ ei, const int* __restrict__ sflag,
                              int* __restrict__ cnt) {
  int e = blockIdx.x * 256 + threadIdx.x;
  if (e < NE) {
    int s = *sflag;
    atomicAdd(&cnt[ei[(size_t)s * (NE + e)]], 1);
  }
}

// single block, 1024 threads: exclusive prefix sum of cnt -> rowptr, ofs
__global__ __launch_bounds__(1024) void scan_k(const int* __restrict__ cnt,
                                               int* __restrict__ rowptr, int* __restrict__ ofs) {
  __shared__ int part[1024];
  int t = threadIdx.x;
  int base = t * 20;
  int loc[20];
  int s = 0;
#pragma unroll
  for (int i = 0; i < 20; i++) {
    int v = (base + i < NN) ? cnt[base + i] : 0;
    loc[i] = s; s += v;
  }
  part[t] = s;
  __syncthreads();
  for (int d = 1; d < 1024; d <<= 1) {
    int v = (t >= d) ? part[t - d] : 0;
    __syncthreads();
    part[t] += v;
    __syncthreads();
  }
  int excl = (t > 0) ? part[t - 1] : 0;
#pragma unroll
  for (int i = 0; i < 20; i++)
    if (base + i < NN) { rowptr[base + i] = excl + loc[i]; ofs[base + i] = excl + loc[i]; }
  if (t == 1023) rowptr[NN] = part[1023];
}

__global__ void scatter_k(const int* __restrict__ ei, const int* __restrict__ sflag,
                          int* __restrict__ ofs, int* __restrict__ perm) {
  int e = blockIdx.x * 256 + threadIdx.x;
  if (e < NE) {
    int s = *sflag;
    int c = ei[(size_t)s * (NE + e)];
    perm[atomicAdd(&ofs[c], 1)] = e;
  }
}

// mean over each node's edges of h (bf16 [E,1024]) -> sbar (bf16 [N,1024])
__global__ void seg_mean_k(const u16* __restrict__ h, const int* __restrict__ rowptr,
                           const int* __restrict__ perm, u16* __restrict__ sbar) {
  int n = blockIdx.x, t = threadIdx.x;
  int beg = rowptr[n], end = rowptr[n + 1];
  float a0 = 0, a1 = 0, a2 = 0, a3 = 0;
  for (int i = beg; i < end; i++) {
    int e = perm[i];
    ushort4 v = *(const ushort4*)(h + (size_t)e * DD + t * 4);
    a0 += bf2f(v.x); a1 += bf2f(v.y); a2 += bf2f(v.z); a3 += bf2f(v.w);
  }
  float inv = (end > beg) ? 1.0f / (float)(end - beg) : 0.0f;
  ushort4 o;
  o.x = f2bf(a0 * inv); o.y = f2bf(a1 * inv); o.z = f2bf(a2 * inv); o.w = f2bf(a3 * inv);
  *(ushort4*)(sbar + (size_t)n * DD + t * 4) = o;
}

// C[M,1024] = A(bf16 [m][k]) @ B^T(bf16 [n][k]); all operands DMA-staged.
// LDS layout: 16B chunk (row,kc) at chunk index row*4 + (kc ^ ((row>>1)&3)).
// EPI 0: Cout(f32) = acc + bias
// EPI 1: Hout(bf16)[e] = relu(acc + P[row[e]])   (edge GEMM)
// EPI 2: Cbf = acc + (cnt>0 ? bias : 0)
// EPI 3: Cbf = relu(acc + bias)
// EPI 4: Cbf = acc + bias
template <int EPI, int NSRC>
__global__ __launch_bounds__(256) void gemm_k(
    const u16* __restrict__ A0, const u16* __restrict__ A1,
    const u16* __restrict__ B0, const u16* __restrict__ B1, int M,
    const float* __restrict__ bias, float* __restrict__ Cout, u16* __restrict__ Cbf,
    const u16* __restrict__ Pg, u16* __restrict__ Hout,
    const int* __restrict__ eidx, const int* __restrict__ sflag,
    const int* __restrict__ cnt) {
  __shared__ __align__(16) u16 As[128 * 32];
  __shared__ __align__(16) u16 Bs[128 * 32];

  const int tid = threadIdx.x;
  const int lane = tid & 63;
  const int wv = tid >> 6;
  const int wm = wv >> 1, wn = wv & 1;  // 2x2 waves, 64x64 each
  const int mblk = blockIdx.y, nblk = blockIdx.x;
  const int lrow = lane & 15, kq = lane >> 4;

  int ss = 1;
  if constexpr (EPI == 1) ss = *sflag;

  // DMA staging precompute: segment s = wv*2+r covers chunks s*64..s*64+63
  size_t a_goff[2], b_goff[2];
  u16 *a_lb[2], *b_lb[2];
#pragma unroll
  for (int r = 0; r < 2; r++) {
    int p = (wv * 2 + r) * 64 + lane;
    int row = p >> 2, c = p & 3;
    int kc = c ^ ((row >> 1) & 3);
    a_goff[r] = (size_t)min(mblk * 128 + row, M - 1) * DD + kc * 8;
    b_goff[r] = (size_t)(nblk * 128 + row) * DD + kc * 8;
    a_lb[r] = &As[(wv * 2 + r) * 512];
    b_lb[r] = &Bs[(wv * 2 + r) * 512];
  }

  // fragment LDS offsets (u16 units)
  int a_fo[4], b_fo[4];
#pragma unroll
  for (int i = 0; i < 4; i++) {
    int m = wm * 64 + i * 16 + lrow;
    a_fo[i] = (m * 4 + (kq ^ ((m >> 1) & 3))) * 8;
    int n = wn * 64 + i * 16 + lrow;
    b_fo[i] = (n * 4 + (kq ^ ((n >> 1) & 3))) * 8;
  }

  f32x4 acc[4][4] = {};

  for (int src = 0; src < NSRC; src++) {
    const u16* Ag = src ? A1 : A0;
    const u16* Bg = src ? B1 : B0;
    for (int kt = 0; kt < DD / 32; kt++) {
#pragma unroll
      for (int r = 0; r < 2; r++) {
        lds_dma16(Ag + a_goff[r] + (size_t)kt * 32, a_lb[r]);
        lds_dma16(Bg + b_goff[r] + (size_t)kt * 32, b_lb[r]);
      }
      __syncthreads();
      bf16x8 af[4], bf[4];
#pragma unroll
      for (int i = 0; i < 4; i++) {
        af[i] = *(const bf16x8*)&As[a_fo[i]];
        bf[i] = *(const bf16x8*)&Bs[b_fo[i]];
      }
#pragma unroll
      for (int i = 0; i < 4; i++)
#pragma unroll
        for (int j = 0; j < 4; j++)
          acc[i][j] = __builtin_amdgcn_mfma_f32_16x16x32_bf16(af[i], bf[j], acc[i][j], 0, 0, 0);
      __syncthreads();
    }
  }

  // epilogue: C/D layout col=lane&15, row=(lane>>4)*4+reg
#pragma unroll
  for (int i = 0; i < 4; i++) {
#pragma unroll
    for (int r = 0; r < 4; r++) {
      int grow = mblk * 128 + wm * 64 + i * 16 + kq * 4 + r;
      if (grow >= M) continue;
      int erow = 0;
      if constexpr (EPI == 1) erow = eidx[(size_t)ss * grow];
#pragma unroll
      for (int j = 0; j < 4; j++) {
        int gcol = nblk * 128 + wn * 64 + j * 16 + lrow;
        float v = acc[i][j][r];
        if constexpr (EPI == 0) {
          Cout[(size_t)grow * DD + gcol] = v + bias[gcol];
        } else if constexpr (EPI == 1) {
          float z = fmaxf(v + bf2f(Pg[(size_t)erow * DD + gcol]), 0.0f);
          Hout[(size_t)grow * DD + gcol] = f2bf(z);
        } else if constexpr (EPI == 2) {
          float b = (cnt[grow] > 0) ? bias[gcol] : 0.0f;
          Cbf[(size_t)grow * DD + gcol] = f2bf(v + b);
        } else if constexpr (EPI == 3) {
          Cbf[(size_t)grow * DD + gcol] = f2bf(fmaxf(v + bias[gcol], 0.0f));
        } else {
          Cbf[(size_t)grow * DD + gcol] = f2bf(v + bias[gcol]);
        }
      }
    }
  }
}

extern "C" void kernel_launch(void* const* d_in, const int* in_sizes, int n_in,
                              void* d_out, int out_size, void* d_ws, size_t ws_size,
                              hipStream_t stream) {
  const float* x   = (const float*)d_in[0];
  const int*   ei  = (const int*)d_in[1];
  const float* ea  = (const float*)d_in[2];
  const float* W1a = (const float*)d_in[3];
  const float* b1a = (const float*)d_in[4];
  const float* W1b = (const float*)d_in[5];
  const float* b1b = (const float*)d_in[6];
  const float* W2a = (const float*)d_in[7];
  const float* b2a = (const float*)d_in[8];
  const float* W2b = (const float*)d_in[9];
  const float* b2b = (const float*)d_in[10];
  float* out = (float*)d_out;

  char* ws = (char*)d_ws;
  size_t off = 0;
  const size_t WSZ = (size_t)DD * DD;
  u16* W1aT_t = (u16*)(ws + off); off += WSZ * 2;
  u16* W1aT_b = (u16*)(ws + off); off += WSZ * 2;
  u16* W1bT   = (u16*)(ws + off); off += WSZ * 2;
  u16* W2aT_t = (u16*)(ws + off); off += WSZ * 2;
  u16* W2aT_b = (u16*)(ws + off); off += WSZ * 2;
  u16* W2bT   = (u16*)(ws + off); off += WSZ * 2;
  u16* xb   = (u16*)(ws + off); off += (size_t)NN * DD * 2;
  u16* eb   = (u16*)(ws + off); off += (size_t)NE * DD * 2;  // ea in bf16
  u16* bufP = (u16*)(ws + off); off += (size_t)NN * DD * 2;  // P -> Sbar -> out2
  u16* bufM = (u16*)(ws + off); off += (size_t)NN * DD * 2;  // M
  u16* h    = (u16*)(ws + off); off += (size_t)NE * DD * 2;
  int* cnt    = (int*)(ws + off); off += (size_t)NN * 4;
  int* rowptr = (int*)(ws + off); off += (size_t)(NN + 1) * 4;
  int* ofs    = (int*)(ws + off); off += (size_t)NN * 4;
  int* perm   = (int*)(ws + off); off += (size_t)NE * 4;
  int* sflag  = (int*)(ws + off); off += 256;
  if (ws_size < off) return;

  dim3 tb(256);
  dim3 tg(32, 32);
  transpose_cvt_k<<<tg, tb, 0, stream>>>(W1a, W1aT_t);
  transpose_cvt_k<<<tg, tb, 0, stream>>>(W1a + WSZ, W1aT_b);
  transpose_cvt_k<<<tg, tb, 0, stream>>>(W1b, W1bT);
  transpose_cvt_k<<<tg, tb, 0, stream>>>(W2a, W2aT_t);
  transpose_cvt_k<<<tg, tb, 0, stream>>>(W2a + WSZ, W2aT_b);
  transpose_cvt_k<<<tg, tb, 0, stream>>>(W2b, W2bT);

  cvt_bf16_k<<<NN * DD / 4 / 256, tb, 0, stream>>>((const float4*)x, (ushort4*)xb, NN * DD / 4);
  cvt_bf16_k<<<NE * DD / 4 / 256, tb, 0, stream>>>((const float4*)ea, (ushort4*)eb, NE * DD / 4);

  detect_stride_k<<<1, 64, 0, stream>>>(ei, sflag);
  hipMemsetAsync(cnt, 0, (size_t)NN * 4, stream);
  count_edges_k<<<(NE + 255) / 256, tb, 0, stream>>>(ei, sflag, cnt);
  scan_k<<<1, 1024, 0, stream>>>(cnt, rowptr, ofs);
  scatter_k<<<(NE + 255) / 256, tb, 0, stream>>>(ei, sflag, ofs, perm);

  dim3 gN(8, (NN + 127) / 128);
  dim3 gE(8, NE / 128);

  // G1: P = xb @ W1a_top + b1a -> bufP (bf16)
  gemm_k<4, 1><<<gN, tb, 0, stream>>>(xb, nullptr, W1aT_t, nullptr, NN,
                                      b1a, nullptr, bufP, nullptr, nullptr,
                                      nullptr, nullptr, nullptr);
  // G2: h = relu(eb @ W1a_bot + P[row]) -> h (bf16)
  gemm_k<1, 1><<<gE, tb, 0, stream>>>(eb, nullptr, W1aT_b, nullptr, NE,
                                      nullptr, nullptr, nullptr, bufP, h,
                                      ei, sflag, nullptr);
  // Sbar = segment-mean of h -> bufP (P dead)
  seg_mean_k<<<NN, tb, 0, stream>>>(h, rowptr, perm, bufP);
  // G3: M = Sbar @ W1b + mask*b1b -> bufM (bf16)
  gemm_k<2, 1><<<gN, tb, 0, stream>>>(bufP, nullptr, W1bT, nullptr, NN,
                                      b1b, nullptr, bufM, nullptr, nullptr,
                                      nullptr, nullptr, cnt);
  // G4: out2 = relu(xb@W2a_top + M@W2a_bot + b2a) -> bufP (Sbar dead)
  gemm_k<3, 2><<<gN, tb, 0, stream>>>(xb, bufM, W2aT_t, W2aT_b, NN,
                                      b2a, nullptr, bufP, nullptr, nullptr,
                                      nullptr, nullptr, nullptr);
  // G5: out = out2 @ W2b + b2b -> d_out (fp32)
  gemm_k<0, 1><<<gN, tb, 0, stream>>>(bufP, nullptr, W2bT, nullptr, NN,
                                      b2b, out, nullptr, nullptr, nullptr,
                                      nullptr, nullptr, nullptr);
}